// Round 6
// baseline (1157.509 us; speedup 1.0000x reference)
//
#include <hip/hip_runtime.h>

#define B_ 4
#define N_ 4096
#define D_ 1024
#define E_ 8
#define TOPK_ 2

typedef float f32x4 __attribute__((ext_vector_type(4)));

// ws layout (bytes):
//   [0,       131072)  idx  int[B*N*2]   top-2 expert indices
//   [131072,  262144)  gp   float[B*N*2] probs of chosen experts
//   [262144,  262404)  acc  float[65]    zsum, psum[4*8], cnt[4*8]

__global__ __launch_bounds__(256) void k_router_gemm(
    const float* __restrict__ x,     // [B,N,D]
    const float* __restrict__ w,     // [D,E] row-major
    int*   __restrict__ idx_out,     // [B*N*2]
    float* __restrict__ gp_out,      // [B*N*2]
    float* __restrict__ acc)         // [65]
{
    __shared__ float Wt[E_][D_];     // 32 KB, transposed gate
    __shared__ float psumL[B_][E_];
    __shared__ float cntL[B_][E_];
    __shared__ float zL;
    const int tid = threadIdx.x;

    for (int i = tid; i < D_ * E_; i += 256) Wt[i & 7][i >> 3] = w[i];
    if (tid < B_ * E_) { psumL[tid >> 3][tid & 7] = 0.f; cntL[tid >> 3][tid & 7] = 0.f; }
    if (tid == 0) zL = 0.f;
    __syncthreads();

    const int lane = tid & 63;
    const int gw   = blockIdx.x * 4 + (tid >> 6);
    const int nw   = gridDim.x * 4;

    for (int t = gw; t < B_ * N_; t += nw) {
        const int b = t >> 12;
        const float* xp = x + (size_t)t * D_;
        float a[E_];
        #pragma unroll
        for (int e = 0; e < E_; ++e) a[e] = 0.f;

        // float4 token loads (1KB/wave/instr) + b128 LDS reads (16B-stride, conflict-free)
        #pragma unroll
        for (int j = 0; j < D_ / 256; ++j) {
            const int d = j * 256 + lane * 4;
            const f32x4 tv = *(const f32x4*)(xp + d);
            #pragma unroll
            for (int e = 0; e < E_; ++e) {
                const f32x4 wv = *(const f32x4*)(&Wt[e][d]);
                a[e] += tv.x * wv.x + tv.y * wv.y + tv.z * wv.z + tv.w * wv.w;
            }
        }
        // 64-lane butterfly reduce, all lanes end with full logits
        #pragma unroll
        for (int e = 0; e < E_; ++e) {
            float v = a[e];
            #pragma unroll
            for (int off = 32; off >= 1; off >>= 1) v += __shfl_xor(v, off);
            a[e] = v;
        }
        // softmax + logsumexp (redundant on all lanes, uniform)
        float m = a[0];
        #pragma unroll
        for (int e = 1; e < E_; ++e) m = fmaxf(m, a[e]);
        float ex[E_], s = 0.f;
        #pragma unroll
        for (int e = 0; e < E_; ++e) { ex[e] = expf(a[e] - m); s += ex[e]; }
        const float inv = 1.f / s;
        float p[E_];
        #pragma unroll
        for (int e = 0; e < E_; ++e) p[e] = ex[e] * inv;
        const float z = m + logf(s);

        // top-2 on probs, ties -> lowest index (strict > keeps first max)
        int i1 = 0; float p1 = p[0];
        #pragma unroll
        for (int e = 1; e < E_; ++e) if (p[e] > p1) { p1 = p[e]; i1 = e; }
        int i2 = (i1 == 0) ? 1 : 0; float p2 = p[i2];
        #pragma unroll
        for (int e = 0; e < E_; ++e) if (e != i1 && p[e] > p2) { p2 = p[e]; i2 = e; }

        if (lane == 0) {
            idx_out[t * 2]     = i1;
            idx_out[t * 2 + 1] = i2;
            gp_out[t * 2]      = p1;
            gp_out[t * 2 + 1]  = p2;
            atomicAdd(&zL, z * z);
        }
        if (lane < E_) {
            atomicAdd(&psumL[b][lane], p[lane]);
            if (lane == i1 || lane == i2) atomicAdd(&cntL[b][lane], 1.f);
        }
    }
    __syncthreads();
    if (tid == 0) atomicAdd(&acc[0], zL);
    if (tid < 32) atomicAdd(&acc[1 + tid], psumL[tid >> 3][tid & 7]);
    if (tid >= 32 && tid < 64) { int q = tid - 32; atomicAdd(&acc[33 + q], cntL[q >> 3][q & 7]); }
}

// One wave per batch: sequential chunked scan over the topk-major stream.
// Rank computed via ballot/popcount; hot output entries written DIRECTLY
// (d_out already zeroed), eliminating the separate scatter kernel.
__global__ __launch_bounds__(64) void k_router_priority(
    const int* __restrict__ idx,     // [B*N*2]
    const float* __restrict__ gp,    // [B*N*2]
    const float* __restrict__ acc,   // [65]
    float*     __restrict__ out,     // [2*B*N*E*C + 2]
    int cap)
{
    const int b = blockIdx.x;
    const int lane = threadIdx.x;
    const size_t planesz = (size_t)E_ * (size_t)cap;
    const size_t combbase = (size_t)B_ * N_ * planesz;
    int run[E_];
    #pragma unroll
    for (int q = 0; q < E_; ++q) run[q] = 0;

    const unsigned long long below_mask = (lane == 0) ? 0ull : (~0ull >> (64 - lane));

    #pragma unroll 4
    for (int it = 0; it < (TOPK_ * N_) / 64; ++it) {
        const int p = it * 64 + lane;
        const int k = p >> 12;           // p / N
        const int n = p & (N_ - 1);
        const size_t s = ((size_t)b * N_ + n) * 2 + k;
        const int e = idx[s];
        int myrank = 0;
        #pragma unroll
        for (int q = 0; q < E_; ++q) {
            const unsigned long long mask = __ballot(e == q);
            if (e == q) myrank = run[q] + __popcll(mask & below_mask);
            run[q] += __popcll(mask);
        }
        if (myrank < cap) {
            const size_t off = ((size_t)b * N_ + n) * planesz + (size_t)e * cap + myrank;
            out[off] = 1.f;                  // dispatch one-hot
            out[combbase + off] = gp[s];     // combine gate
        }
    }

    if (b == 0 && lane == 0) {
        const float zmean = acc[0] / (float)(B_ * N_);
        float auxv = 0.f;
        #pragma unroll
        for (int i = 0; i < B_ * E_; ++i)
            auxv += (acc[1 + i] / (float)N_) * (acc[33 + i] / (float)N_);
        auxv = auxv / (float)(B_ * E_) * (float)(E_ * E_);
        out[combbase * 2 + 0] = auxv;   // aux_loss
        out[combbase * 2 + 1] = zmean;  // z_loss
    }
}

extern "C" void kernel_launch(void* const* d_in, const int* in_sizes, int n_in,
                              void* d_out, int out_size, void* d_ws, size_t ws_size,
                              hipStream_t stream) {
    const float* x = (const float*)d_in[0];
    const float* w = (const float*)d_in[1];
    // capacity from out_size: out = 2*B*N*E*C + 2 scalars
    const long long C = ((long long)out_size - 2) / ((long long)B_ * N_ * E_ * 2);

    char* ws = (char*)d_ws;
    int*   idx = (int*)(ws);
    float* gp  = (float*)(ws + 131072);
    float* acc = (float*)(ws + 262144);

    // Bulk-zero the output on the rocclr fill path (measured 6.25-6.36 TB/s),
    // then write only the <=65538 nonzero entries.
    (void)hipMemsetAsync(d_out, 0, (size_t)out_size * sizeof(float), stream);
    (void)hipMemsetAsync(acc, 0, 65 * sizeof(float), stream);

    // 1024 blocks x 4 waves = 4 waves/SIMD (4 blocks/CU at 32KB LDS): latency hiding
    k_router_gemm<<<1024, 256, 0, stream>>>(x, w, idx, gp, acc);

    k_router_priority<<<B_, 64, 0, stream>>>(idx, gp, acc, (float*)d_out, (int)C);
}